// Round 1
// baseline (1030.639 us; speedup 1.0000x reference)
//
#include <hip/hip_runtime.h>
#include <math.h>

#define NUM_LEVELS 16
#define T_SIZE (1u << 19)
#define T_MASK (T_SIZE - 1u)
#define PRIME1 2654435761u
#define PRIME2 805459861u

struct ResParams { float r[NUM_LEVELS]; };

// thread = (point n, level l), tid = n*16 + l.
// out is float2* : out2[tid] == out[n*32 + l*2 .. +1]  -> fully coalesced 8B stores.
__global__ __launch_bounds__(256) void hashgrid_fwd_kernel(
    const float* __restrict__ pos,      // [N,3] f32
    const float2* __restrict__ table,   // [L*T] float2 (F=2)
    float2* __restrict__ out,           // [N*16] float2
    ResParams rp, int N)
{
    __shared__ float sres[NUM_LEVELS];
    if (threadIdx.x == 0) {
#pragma unroll
        for (int i = 0; i < NUM_LEVELS; ++i) sres[i] = rp.r[i];
    }
    __syncthreads();

    int tid = blockIdx.x * blockDim.x + threadIdx.x;
    int n = tid >> 4;
    int l = tid & 15;
    if (n >= N) return;

    float px = pos[3 * n + 0];
    float py = pos[3 * n + 1];
    float pz = pos[3 * n + 2];

    // normalized = (p - (-1)) / (2 + 1e-8); float32(2+1e-8) == 2.0f, so *0.5f is exact-identical.
    float nx = (px + 1.0f) * 0.5f;
    float ny = (py + 1.0f) * 0.5f;
    float nz = (pz + 1.0f) * 0.5f;
    const float HI = 0.999999f;  // float32(1.0 - 1e-6), same rounding as numpy
    nx = fminf(fmaxf(nx, 0.0f), HI);
    ny = fminf(fmaxf(ny, 0.0f), HI);
    nz = fminf(fmaxf(nz, 0.0f), HI);

    float res = sres[l];
    float sx = nx * res, sy = ny * res, sz = nz * res;
    float flx = floorf(sx), fly = floorf(sy), flz = floorf(sz);
    float fx = sx - flx, fy = sy - fly, fz = sz - flz;

    unsigned ux = (unsigned)(int)flx;
    unsigned uy = (unsigned)(int)fly;
    unsigned uz = (unsigned)(int)flz;

    // hash(c) = (x*1) ^ (y*PRIME1) ^ (z*PRIME2), exact uint32 wraparound
    unsigned hx0 = ux;            unsigned hx1 = ux + 1u;
    unsigned hy0 = uy * PRIME1;   unsigned hy1 = hy0 + PRIME1;
    unsigned hz0 = uz * PRIME2;   unsigned hz1 = hz0 + PRIME2;

    unsigned base = (unsigned)l * T_SIZE;
    unsigned i000 = base + ((hx0 ^ hy0 ^ hz0) & T_MASK);
    unsigned i001 = base + ((hx0 ^ hy0 ^ hz1) & T_MASK);
    unsigned i010 = base + ((hx0 ^ hy1 ^ hz0) & T_MASK);
    unsigned i011 = base + ((hx0 ^ hy1 ^ hz1) & T_MASK);
    unsigned i100 = base + ((hx1 ^ hy0 ^ hz0) & T_MASK);
    unsigned i101 = base + ((hx1 ^ hy0 ^ hz1) & T_MASK);
    unsigned i110 = base + ((hx1 ^ hy1 ^ hz0) & T_MASK);
    unsigned i111 = base + ((hx1 ^ hy1 ^ hz1) & T_MASK);

    float2 f000 = table[i000];
    float2 f001 = table[i001];
    float2 f010 = table[i010];
    float2 f011 = table[i011];
    float2 f100 = table[i100];
    float2 f101 = table[i101];
    float2 f110 = table[i110];
    float2 f111 = table[i111];

    // trilinear, exact reference ordering: z, then y, then x; a*(1-f)+b*f
    float omz = 1.0f - fz, omy = 1.0f - fy, omx = 1.0f - fx;
    float c00x = f000.x * omz + f001.x * fz;
    float c00y = f000.y * omz + f001.y * fz;
    float c01x = f010.x * omz + f011.x * fz;
    float c01y = f010.y * omz + f011.y * fz;
    float c10x = f100.x * omz + f101.x * fz;
    float c10y = f100.y * omz + f101.y * fz;
    float c11x = f110.x * omz + f111.x * fz;
    float c11y = f110.y * omz + f111.y * fz;

    float c0x = c00x * omy + c01x * fy;
    float c0y = c00y * omy + c01y * fy;
    float c1x = c10x * omy + c11x * fy;
    float c1y = c10y * omy + c11y * fy;

    float2 o;
    o.x = c0x * omx + c1x * fx;
    o.y = c0y * omx + c1y * fx;
    out[tid] = o;
}

extern "C" void kernel_launch(void* const* d_in, const int* in_sizes, int n_in,
                              void* d_out, int out_size, void* d_ws, size_t ws_size,
                              hipStream_t stream) {
    const float*  pos   = (const float*)d_in[0];
    const float2* table = (const float2*)d_in[1];
    float2*       out   = (float2*)d_out;
    int N = in_sizes[0] / 3;

    // Replicate Python's RESOLUTIONS bit-exactly: same libm (glibc) double math.
    // GROWTH = exp((log(2048)-log(16))/15); res[l] = ceil(16 * GROWTH**l)
    ResParams rp;
    double growth = exp((log(2048.0) - log(16.0)) / 15.0);
    for (int l = 0; l < NUM_LEVELS; ++l) {
        rp.r[l] = (float)ceil(16.0 * pow(growth, (double)l));
    }

    long long total = (long long)N * NUM_LEVELS;
    int block = 256;
    int grid = (int)((total + block - 1) / block);
    hashgrid_fwd_kernel<<<grid, block, 0, stream>>>(pos, table, out, rp, N);
}

// Round 2
// 779.898 us; speedup vs baseline: 1.3215x; 1.3215x over previous
//
#include <hip/hip_runtime.h>
#include <math.h>

#define NUM_LEVELS 16
#define T_SIZE (1u << 19)
#define T_MASK (T_SIZE - 1u)
#define PRIME1 2654435761u
#define PRIME2 805459861u

struct ResParams { float r[NUM_LEVELS]; };

__device__ __forceinline__ void hash_interp_one(
    float px, float py, float pz, float res, unsigned base,
    const float2* __restrict__ table, float2* __restrict__ dst)
{
    // normalized = (p+1)/(2+1e-8); float32(2+1e-8)==2.0f so *0.5f is bit-identical
    float nx = (px + 1.0f) * 0.5f;
    float ny = (py + 1.0f) * 0.5f;
    float nz = (pz + 1.0f) * 0.5f;
    const float HI = 0.999999f;
    nx = fminf(fmaxf(nx, 0.0f), HI);
    ny = fminf(fmaxf(ny, 0.0f), HI);
    nz = fminf(fmaxf(nz, 0.0f), HI);

    float sx = nx * res, sy = ny * res, sz = nz * res;
    float flx = floorf(sx), fly = floorf(sy), flz = floorf(sz);
    float fx = sx - flx, fy = sy - fly, fz = sz - flz;

    unsigned ux = (unsigned)(int)flx;
    unsigned uy = (unsigned)(int)fly;
    unsigned uz = (unsigned)(int)flz;

    unsigned hx0 = ux;            unsigned hx1 = ux + 1u;
    unsigned hy0 = uy * PRIME1;   unsigned hy1 = hy0 + PRIME1;
    unsigned hz0 = uz * PRIME2;   unsigned hz1 = hz0 + PRIME2;

    unsigned i000 = base + ((hx0 ^ hy0 ^ hz0) & T_MASK);
    unsigned i001 = base + ((hx0 ^ hy0 ^ hz1) & T_MASK);
    unsigned i010 = base + ((hx0 ^ hy1 ^ hz0) & T_MASK);
    unsigned i011 = base + ((hx0 ^ hy1 ^ hz1) & T_MASK);
    unsigned i100 = base + ((hx1 ^ hy0 ^ hz0) & T_MASK);
    unsigned i101 = base + ((hx1 ^ hy0 ^ hz1) & T_MASK);
    unsigned i110 = base + ((hx1 ^ hy1 ^ hz0) & T_MASK);
    unsigned i111 = base + ((hx1 ^ hy1 ^ hz1) & T_MASK);

    float2 f000 = table[i000];
    float2 f001 = table[i001];
    float2 f010 = table[i010];
    float2 f011 = table[i011];
    float2 f100 = table[i100];
    float2 f101 = table[i101];
    float2 f110 = table[i110];
    float2 f111 = table[i111];

    float omz = 1.0f - fz, omy = 1.0f - fy, omx = 1.0f - fx;
    float c00x = f000.x * omz + f001.x * fz;
    float c00y = f000.y * omz + f001.y * fz;
    float c01x = f010.x * omz + f011.x * fz;
    float c01y = f010.y * omz + f011.y * fz;
    float c10x = f100.x * omz + f101.x * fz;
    float c10y = f100.y * omz + f101.y * fz;
    float c11x = f110.x * omz + f111.x * fz;
    float c11y = f110.y * omz + f111.y * fz;

    float c0x = c00x * omy + c01x * fy;
    float c0y = c00y * omy + c01y * fy;
    float c1x = c10x * omy + c11x * fy;
    float c1y = c10y * omy + c11y * fy;

    dst->x = c0x * omx + c1x * fx;
    dst->y = c0y * omx + c1y * fx;
}

// ---------------- Pass 1: level-partitioned gather, XCD-affine ----------------
// blockIdx.x = chunk*16 + j ; level = j ; XCD = blockIdx%8 = j%8.
// => level l only runs on XCD l%8; XCD x sees only tables {x, x+8} (~4-8 MB) in its 4 MB L2.
// Writes ws[level][n] (float2), fully coalesced.
__global__ __launch_bounds__(256) void hashgrid_gather_kernel(
    const float* __restrict__ pos,      // [N,3]
    const float2* __restrict__ table,   // [L*T]
    float2* __restrict__ ws,            // [L][N]
    ResParams rp, int N)
{
    int j = blockIdx.x & 15;            // level slot; j%8 = XCD
    int chunk = blockIdx.x >> 4;
    int n = chunk * 256 + threadIdx.x;
    if (n >= N) return;

    int level = j;
    float res = rp.r[level];            // scalar (uniform per block)
    unsigned base = (unsigned)level * T_SIZE;

    float px = pos[3 * n + 0];
    float py = pos[3 * n + 1];
    float pz = pos[3 * n + 2];

    float2 o;
    hash_interp_one(px, py, pz, res, base, table, &o);
    ws[level * N + n] = o;
}

// ---------------- Pass 2: transpose ws[L][N] -> out[N][L] via LDS ----------------
// Block handles 64 points. Reads coalesced per level row, writes full output lines.
__global__ __launch_bounds__(256) void hashgrid_transpose_kernel(
    const float2* __restrict__ ws,      // [L][N]
    float2* __restrict__ out,           // [N][L]
    int N)
{
    __shared__ float2 tile[NUM_LEVELS][64 + 1];
    int base = blockIdx.x * 64;
    int t = threadIdx.x;

    // Phase A: 4 iters; 4 level-rows x 64 points per iter, 512B coalesced per row
#pragma unroll
    for (int i = 0; i < 4; ++i) {
        int l = i * 4 + (t >> 6);
        int p = t & 63;
        int n = base + p;
        if (n < N) tile[l][p] = ws[l * N + n];
    }
    __syncthreads();

    // Phase B: 4 iters; write out2[base*16 + g] contiguous (g = i*256 + t)
#pragma unroll
    for (int i = 0; i < 4; ++i) {
        int g = i * 256 + t;
        int p = g >> 4;      // point within tile
        int l = g & 15;      // level
        int n = base + p;
        if (n < N) out[n * NUM_LEVELS + l] = tile[l][p];
    }
}

// ---------------- Fallback: round-0 fused kernel (if ws too small) ----------------
__global__ __launch_bounds__(256) void hashgrid_fused_kernel(
    const float* __restrict__ pos,
    const float2* __restrict__ table,
    float2* __restrict__ out,
    ResParams rp, int N)
{
    int tid = blockIdx.x * blockDim.x + threadIdx.x;
    int n = tid >> 4;
    int l = tid & 15;
    if (n >= N) return;

    float px = pos[3 * n + 0];
    float py = pos[3 * n + 1];
    float pz = pos[3 * n + 2];

    float2 o;
    hash_interp_one(px, py, pz, rp.r[l], (unsigned)l * T_SIZE, table, &o);
    out[tid] = o;
}

extern "C" void kernel_launch(void* const* d_in, const int* in_sizes, int n_in,
                              void* d_out, int out_size, void* d_ws, size_t ws_size,
                              hipStream_t stream) {
    const float*  pos   = (const float*)d_in[0];
    const float2* table = (const float2*)d_in[1];
    float2*       out   = (float2*)d_out;
    int N = in_sizes[0] / 3;

    ResParams rp;
    double growth = exp((log(2048.0) - log(16.0)) / 15.0);
    for (int l = 0; l < NUM_LEVELS; ++l) {
        rp.r[l] = (float)ceil(16.0 * pow(growth, (double)l));
    }

    size_t ws_needed = (size_t)NUM_LEVELS * (size_t)N * sizeof(float2);
    if (ws_size >= ws_needed) {
        float2* ws = (float2*)d_ws;
        int chunks = (N + 255) / 256;
        hashgrid_gather_kernel<<<chunks * NUM_LEVELS, 256, 0, stream>>>(pos, table, ws, rp, N);
        int tblocks = (N + 63) / 64;
        hashgrid_transpose_kernel<<<tblocks, 256, 0, stream>>>(ws, out, N);
    } else {
        long long total = (long long)N * NUM_LEVELS;
        int grid = (int)((total + 255) / 256);
        hashgrid_fused_kernel<<<grid, 256, 0, stream>>>(pos, table, out, rp, N);
    }
}

// Round 3
// 648.531 us; speedup vs baseline: 1.5892x; 1.2026x over previous
//
#include <hip/hip_runtime.h>
#include <math.h>

#define NUM_LEVELS 16
#define T_SIZE (1u << 19)
#define T_MASK (T_SIZE - 1u)
#define PRIME1 2654435761u
#define PRIME2 805459861u

struct ResParams { float r[NUM_LEVELS]; };

typedef float f32x2 __attribute__((ext_vector_type(2)));
typedef float f32x4 __attribute__((ext_vector_type(4)));

__device__ __forceinline__ void nt_store_f2(float2 v, float2* p) {
    f32x2 x; x.x = v.x; x.y = v.y;
    __builtin_nontemporal_store(x, (f32x2*)p);
}
__device__ __forceinline__ float2 nt_load_f2(const float2* p) {
    f32x2 x = __builtin_nontemporal_load((const f32x2*)p);
    float2 r; r.x = x.x; r.y = x.y; return r;
}
__device__ __forceinline__ void nt_store_f4(f32x4 v, float* p) {
    __builtin_nontemporal_store(v, (f32x4*)p);
}
__device__ __forceinline__ f32x4 nt_load_f4(const float* p) {
    return __builtin_nontemporal_load((const f32x4*)p);
}

// Compute the 8 corner hash indices + fractional weights for one point/level.
struct CornerSet {
    unsigned idx[8];
    float fx, fy, fz;
};

__device__ __forceinline__ void calc_corners(
    float px, float py, float pz, float res, unsigned base, CornerSet& cs)
{
    // normalized = (p+1)/(2+1e-8); float32(2+1e-8)==2.0f so *0.5f is bit-identical
    float nx = (px + 1.0f) * 0.5f;
    float ny = (py + 1.0f) * 0.5f;
    float nz = (pz + 1.0f) * 0.5f;
    const float HI = 0.999999f;  // float32(1.0 - 1e-6)
    nx = fminf(fmaxf(nx, 0.0f), HI);
    ny = fminf(fmaxf(ny, 0.0f), HI);
    nz = fminf(fmaxf(nz, 0.0f), HI);

    float sx = nx * res, sy = ny * res, sz = nz * res;
    float flx = floorf(sx), fly = floorf(sy), flz = floorf(sz);
    cs.fx = sx - flx; cs.fy = sy - fly; cs.fz = sz - flz;

    unsigned ux = (unsigned)(int)flx;
    unsigned uy = (unsigned)(int)fly;
    unsigned uz = (unsigned)(int)flz;

    unsigned hx0 = ux;            unsigned hx1 = ux + 1u;
    unsigned hy0 = uy * PRIME1;   unsigned hy1 = hy0 + PRIME1;
    unsigned hz0 = uz * PRIME2;   unsigned hz1 = hz0 + PRIME2;

    cs.idx[0] = base + ((hx0 ^ hy0 ^ hz0) & T_MASK);
    cs.idx[1] = base + ((hx0 ^ hy0 ^ hz1) & T_MASK);
    cs.idx[2] = base + ((hx0 ^ hy1 ^ hz0) & T_MASK);
    cs.idx[3] = base + ((hx0 ^ hy1 ^ hz1) & T_MASK);
    cs.idx[4] = base + ((hx1 ^ hy0 ^ hz0) & T_MASK);
    cs.idx[5] = base + ((hx1 ^ hy0 ^ hz1) & T_MASK);
    cs.idx[6] = base + ((hx1 ^ hy1 ^ hz0) & T_MASK);
    cs.idx[7] = base + ((hx1 ^ hy1 ^ hz1) & T_MASK);
}

__device__ __forceinline__ float2 trilerp(const float2 f[8], float fx, float fy, float fz)
{
    float omz = 1.0f - fz, omy = 1.0f - fy, omx = 1.0f - fx;
    float c00x = f[0].x * omz + f[1].x * fz;
    float c00y = f[0].y * omz + f[1].y * fz;
    float c01x = f[2].x * omz + f[3].x * fz;
    float c01y = f[2].y * omz + f[3].y * fz;
    float c10x = f[4].x * omz + f[5].x * fz;
    float c10y = f[4].y * omz + f[5].y * fz;
    float c11x = f[6].x * omz + f[7].x * fz;
    float c11y = f[6].y * omz + f[7].y * fz;
    float c0x = c00x * omy + c01x * fy;
    float c0y = c00y * omy + c01y * fy;
    float c1x = c10x * omy + c11x * fy;
    float c1y = c10y * omy + c11y * fy;
    float2 o;
    o.x = c0x * omx + c1x * fx;
    o.y = c0y * omx + c1y * fx;
    return o;
}

// ---------------- Pass 1: level-phased gather (level = blockIdx.y) ----------------
// Dispatch is x-fastest => all CUs process one level at a time; every XCD caches the
// current 4 MB table in its own L2 (replicated via L3). 2 points/thread for MLP.
// ws stores are non-temporal so they don't evict the table from L2.
__global__ __launch_bounds__(256) void hashgrid_gather_kernel(
    const float* __restrict__ pos,      // [N,3]
    const float2* __restrict__ table,   // [L*T]
    float2* __restrict__ ws,            // [L][N]
    ResParams rp, int N)
{
    int level = blockIdx.y;
    int t = threadIdx.x;
    int n0 = blockIdx.x * 512 + t;
    int n1 = n0 + 256;
    bool v0 = n0 < N;
    bool v1 = n1 < N;
    if (!v0) return;

    float res = rp.r[level];
    unsigned base = (unsigned)level * T_SIZE;

    float px0 = pos[3 * n0 + 0], py0 = pos[3 * n0 + 1], pz0 = pos[3 * n0 + 2];
    int m1 = v1 ? n1 : n0;  // safe address for inactive second point
    float px1 = pos[3 * m1 + 0], py1 = pos[3 * m1 + 1], pz1 = pos[3 * m1 + 2];

    CornerSet c0, c1;
    calc_corners(px0, py0, pz0, res, base, c0);
    calc_corners(px1, py1, pz1, res, base, c1);

    // Issue all 16 gathers before any use -> 16 outstanding loads per thread.
    float2 f0[8], f1[8];
#pragma unroll
    for (int i = 0; i < 8; ++i) f0[i] = table[c0.idx[i]];
#pragma unroll
    for (int i = 0; i < 8; ++i) f1[i] = table[c1.idx[i]];

    float2 o0 = trilerp(f0, c0.fx, c0.fy, c0.fz);
    float2 o1 = trilerp(f1, c1.fx, c1.fy, c1.fz);

    nt_store_f2(o0, &ws[(size_t)level * N + n0]);
    if (v1) nt_store_f2(o1, &ws[(size_t)level * N + n1]);
}

// ---------------- Pass 2: transpose ws[L][N] -> out[N][L], 256-pt tiles, float4 ----
__global__ __launch_bounds__(256) void hashgrid_transpose_kernel(
    const float2* __restrict__ ws,      // [L][N]
    float* __restrict__ out,            // [N][32] floats
    int N)
{
    __shared__ float2 tile[NUM_LEVELS][257];  // +1 pad: phase-B banks conflict-free
    int base = blockIdx.x * 256;
    int t = threadIdx.x;
    int rem = N - base;                 // points in this tile (<=256)

    // Phase A: 16 rows x 128 float4 (2 points each) = 2048 reads, 8 iters
#pragma unroll
    for (int i = 0; i < 8; ++i) {
        int g = i * 256 + t;
        int l = g >> 7;                 // row
        int k = g & 127;                // float4 index within row
        int p = 2 * k;
        if (p + 1 < rem) {
            f32x4 v = nt_load_f4((const float*)&ws[(size_t)l * N + base + p]);
            float2 a; a.x = v.x; a.y = v.y;
            float2 b; b.x = v.z; b.y = v.w;
            tile[l][p] = a;
            tile[l][p + 1] = b;
        } else if (p < rem) {
            tile[l][p] = nt_load_f2(&ws[(size_t)l * N + base + p]);
        }
    }
    __syncthreads();

    // Phase B: per point, 8 float4 (levels 2m,2m+1). 2048 writes, 8 iters, contiguous.
#pragma unroll
    for (int i = 0; i < 8; ++i) {
        int g = i * 256 + t;
        int p = g >> 3;                 // point within tile
        int m = g & 7;                  // float4 slot (levels 2m, 2m+1)
        if (p < rem) {
            float2 a = tile[2 * m][p];
            float2 b = tile[2 * m + 1][p];
            f32x4 v; v.x = a.x; v.y = a.y; v.z = b.x; v.w = b.y;
            nt_store_f4(v, &out[((size_t)(base + p) * 32) + m * 4]);
        }
    }
}

// ---------------- Fallback (ws too small): fused single-pass ----------------
__global__ __launch_bounds__(256) void hashgrid_fused_kernel(
    const float* __restrict__ pos,
    const float2* __restrict__ table,
    float2* __restrict__ out,
    ResParams rp, int N)
{
    int tid = blockIdx.x * blockDim.x + threadIdx.x;
    int n = tid >> 4;
    int l = tid & 15;
    if (n >= N) return;
    float px = pos[3 * n + 0], py = pos[3 * n + 1], pz = pos[3 * n + 2];
    CornerSet c;
    calc_corners(px, py, pz, rp.r[l], (unsigned)l * T_SIZE, c);
    float2 f[8];
#pragma unroll
    for (int i = 0; i < 8; ++i) f[i] = table[c.idx[i]];
    out[tid] = trilerp(f, c.fx, c.fy, c.fz);
}

extern "C" void kernel_launch(void* const* d_in, const int* in_sizes, int n_in,
                              void* d_out, int out_size, void* d_ws, size_t ws_size,
                              hipStream_t stream) {
    const float*  pos   = (const float*)d_in[0];
    const float2* table = (const float2*)d_in[1];
    int N = in_sizes[0] / 3;

    ResParams rp;
    double growth = exp((log(2048.0) - log(16.0)) / 15.0);
    for (int l = 0; l < NUM_LEVELS; ++l) {
        rp.r[l] = (float)ceil(16.0 * pow(growth, (double)l));
    }

    size_t ws_needed = (size_t)NUM_LEVELS * (size_t)N * sizeof(float2);
    if (ws_size >= ws_needed) {
        float2* ws = (float2*)d_ws;
        int chunks = (N + 511) / 512;
        dim3 grid(chunks, NUM_LEVELS);
        hashgrid_gather_kernel<<<grid, 256, 0, stream>>>(pos, table, ws, rp, N);
        int tblocks = (N + 255) / 256;
        hashgrid_transpose_kernel<<<tblocks, 256, 0, stream>>>(ws, (float*)d_out, N);
    } else {
        long long total = (long long)N * NUM_LEVELS;
        int grid = (int)((total + 255) / 256);
        hashgrid_fused_kernel<<<grid, 256, 0, stream>>>(pos, table, (float2*)d_out, rp, N);
    }
}